// Round 6
// baseline (361.360 us; speedup 1.0000x reference)
//
#include <hip/hip_runtime.h>
#include <math.h>

// KNN-attention: N=50000, K=16 neighbors, HIDDEN=256 = 8 heads x 32 dim.
// One wave64 per point: lane = head*8 + (d/4); each lane owns a float4 slice.
//
// Round-6: sched_barrier(0) failed to hold (VGPR stayed 56 — IR-level sinking
// moved gathers back to their uses; sched_barrier only fences the machine
// scheduler). Use asm volatile("" ::: "memory") instead: a memory-clobbering
// asm may alias the gathered memory, so no compiler stage may sink a load
// past it. All 32 gather results must be live across the fence (~128 VGPRs),
// forcing 32 loads in flight per wave instead of 1.

#define KNN_K      16
#define HIDDEN_    256
#define HEAD_DIM_  32
#define SCALE_     0.17677669529663687f   // 32^-0.5

__global__ __launch_bounds__(256) void knn_attn_kernel(
    const float* __restrict__ keys,
    const float* __restrict__ queries,
    const float* __restrict__ values,
    const int*   __restrict__ nbr,
    float*       __restrict__ out,
    int n_pts)
{
    const int gtid = blockIdx.x * blockDim.x + threadIdx.x;
    const int pt   = gtid >> 6;            // one wave64 per point
    const int lane = threadIdx.x & 63;
    if (pt >= n_pts) return;

    const int h   = lane >> 3;             // head 0..7
    const int d4  = (lane & 7) << 2;       // float4 slot within head
    const int col = h * HEAD_DIM_ + d4;    // column 0..255 (x4)

    // Wave-uniform neighbor indices: one broadcast int4 fetch per 4 indices.
    const int4* nb4 = reinterpret_cast<const int4*>(nbr + (size_t)pt * KNN_K);
    const int4 i0 = nb4[0], i1 = nb4[1], i2 = nb4[2], i3 = nb4[3];
    const int idx[KNN_K] = { i0.x,i0.y,i0.z,i0.w, i1.x,i1.y,i1.z,i1.w,
                             i2.x,i2.y,i2.z,i2.w, i3.x,i3.y,i3.z,i3.w };

    const float4 q4 = *reinterpret_cast<const float4*>(
        queries + (size_t)pt * HIDDEN_ + col);

    // ---- issue ALL 32 gathers ----
    float4 kr[KNN_K];
    #pragma unroll
    for (int k = 0; k < KNN_K; ++k)
        kr[k] = *reinterpret_cast<const float4*>(
            keys + (size_t)idx[k] * HIDDEN_ + col);

    float4 vr[KNN_K];
    #pragma unroll
    for (int k = 0; k < KNN_K; ++k)
        vr[k] = *reinterpret_cast<const float4*>(
            values + (size_t)idx[k] * HIDDEN_ + col);

    // Memory-clobber fence: the asm may write the gathered memory, so no
    // compiler pass (IR or machine-level) may sink a gather load below this
    // point. All 32 loads are issued; results stay live in VGPRs.
    asm volatile("" ::: "memory");

    // ---- scores: per-head dot over 32 dims, reduced across the 8-lane group.
    float s[KNN_K];
    #pragma unroll
    for (int k = 0; k < KNN_K; ++k) {
        float p = q4.x * kr[k].x + q4.y * kr[k].y
                + q4.z * kr[k].z + q4.w * kr[k].w;
        p += __shfl_xor(p, 1, 64);
        p += __shfl_xor(p, 2, 64);
        p += __shfl_xor(p, 4, 64);
        s[k] = p * SCALE_;
    }

    // ---- softmax over K=16 in registers; normalize once at the end ----
    float m = s[0];
    #pragma unroll
    for (int k = 1; k < KNN_K; ++k) m = fmaxf(m, s[k]);
    float denom = 0.f;
    #pragma unroll
    for (int k = 0; k < KNN_K; ++k) { s[k] = __expf(s[k] - m); denom += s[k]; }
    const float inv = 1.0f / denom;

    float4 acc = make_float4(0.f, 0.f, 0.f, 0.f);
    #pragma unroll
    for (int k = 0; k < KNN_K; ++k) {
        acc.x += s[k] * vr[k].x; acc.y += s[k] * vr[k].y;
        acc.z += s[k] * vr[k].z; acc.w += s[k] * vr[k].w;
    }
    acc.x *= inv; acc.y *= inv; acc.z *= inv; acc.w *= inv;

    *reinterpret_cast<float4*>(out + (size_t)pt * HIDDEN_ + col) = acc;
}

extern "C" void kernel_launch(void* const* d_in, const int* in_sizes, int n_in,
                              void* d_out, int out_size, void* d_ws, size_t ws_size,
                              hipStream_t stream) {
    const float* keys    = (const float*)d_in[0];
    const float* queries = (const float*)d_in[1];
    const float* values  = (const float*)d_in[2];
    const int*   nbr     = (const int*)d_in[3];
    float*       out     = (float*)d_out;

    const int n_pts = in_sizes[3] / KNN_K;       // 50000
    const int waves_per_block = 4;               // 256 threads
    const int blocks = (n_pts + waves_per_block - 1) / waves_per_block;
    knn_attn_kernel<<<blocks, 256, 0, stream>>>(keys, queries, values, nbr, out, n_pts);
}

// Round 7
// 358.480 us; speedup vs baseline: 1.0080x; 1.0080x over previous
//
#include <hip/hip_runtime.h>
#include <math.h>

// KNN-attention: N=50000, K=16 neighbors, HIDDEN=256 = 8 heads x 32 dim.
// One wave64 per point: lane = head*8 + (d/4); each lane owns a float4 slice.
//
// Round-7: compiler-level fences (sched_barrier, asm memory clobber) both
// failed to prevent load-sinking (VGPR stayed 56; noalias+readonly lets AA
// sink loads past a memory clobber). So the gathers are now inline-asm
// global_load_dwordx4: volatile asm preserves program order at every stage,
// guaranteeing 16 loads in flight before the first s_waitcnt. Staged K-phase
// then V-phase keeps peak VGPR ~128 (16 waves/CU). Explicit s_waitcnt +
// sched_barrier(0) pairs stop consumers hoisting above the wait (rule #18).

#define KNN_K      16
#define HIDDEN_    256
#define SCALE_     0.17677669529663687f   // 32^-0.5

typedef float f32x4 __attribute__((ext_vector_type(4)));

__global__ __launch_bounds__(256) void knn_attn_kernel(
    const float* __restrict__ keys,
    const float* __restrict__ queries,
    const float* __restrict__ values,
    const int*   __restrict__ nbr,
    float*       __restrict__ out,
    int n_pts)
{
    const int gtid = blockIdx.x * blockDim.x + threadIdx.x;
    const int pt   = gtid >> 6;            // one wave64 per point
    const int lane = threadIdx.x & 63;
    if (pt >= n_pts) return;

    const int h   = lane >> 3;             // head 0..7
    const int d4  = (lane & 7) << 2;       // float4 slot within head
    const int col = h * 32 + d4;           // column 0..255 (x4)

    // Wave-uniform neighbor indices: one broadcast int4 fetch per 4 indices.
    const int4* nb4 = reinterpret_cast<const int4*>(nbr + (size_t)pt * KNN_K);
    const int4 i0 = nb4[0], i1 = nb4[1], i2 = nb4[2], i3 = nb4[3];
    const int idx[KNN_K] = { i0.x,i0.y,i0.z,i0.w, i1.x,i1.y,i1.z,i1.w,
                             i2.x,i2.y,i2.z,i2.w, i3.x,i3.y,i3.z,i3.w };

    const float4 q4 = *reinterpret_cast<const float4*>(
        queries + (size_t)pt * HIDDEN_ + col);

    // ---- phase 1: 16 K-row gathers, issued back-to-back via volatile asm ----
    f32x4 kr[KNN_K];
    #pragma unroll
    for (int k = 0; k < KNN_K; ++k) {
        const float* kp = keys + (size_t)idx[k] * HIDDEN_ + col;
        asm volatile("global_load_dwordx4 %0, %1, off"
                     : "=v"(kr[k]) : "v"(kp));
    }
    // Wait for ALL 16 at once (one stall instead of 16 serialized ones).
    asm volatile("s_waitcnt vmcnt(0)" ::: "memory");
    __builtin_amdgcn_sched_barrier(0);   // consumers may not hoist above wait

    // Per-lane partial dots; kr dies here, freeing its 64 VGPRs.
    float s[KNN_K];
    #pragma unroll
    for (int k = 0; k < KNN_K; ++k)
        s[k] = q4.x * kr[k].x + q4.y * kr[k].y
             + q4.z * kr[k].z + q4.w * kr[k].w;

    // ---- phase 2: issue 16 V-row gathers, then hide their latency under
    // the shuffle-reduce + softmax. ----
    f32x4 vr[KNN_K];
    #pragma unroll
    for (int k = 0; k < KNN_K; ++k) {
        const float* vp = values + (size_t)idx[k] * HIDDEN_ + col;
        asm volatile("global_load_dwordx4 %0, %1, off"
                     : "=v"(vr[k]) : "v"(vp));
    }

    // Cross-lane reduce within each 8-lane head group (16 independent chains).
    #pragma unroll
    for (int k = 0; k < KNN_K; ++k) {
        float p = s[k];
        p += __shfl_xor(p, 1, 64);
        p += __shfl_xor(p, 2, 64);
        p += __shfl_xor(p, 4, 64);
        s[k] = p * SCALE_;
    }

    // Softmax over K=16 in registers; normalize once at the end.
    float m = s[0];
    #pragma unroll
    for (int k = 1; k < KNN_K; ++k) m = fmaxf(m, s[k]);
    float denom = 0.f;
    #pragma unroll
    for (int k = 0; k < KNN_K; ++k) { s[k] = __expf(s[k] - m); denom += s[k]; }
    const float inv = 1.0f / denom;

    asm volatile("s_waitcnt vmcnt(0)" ::: "memory");
    __builtin_amdgcn_sched_barrier(0);   // vr consumers stay below the wait

    float4 acc = make_float4(0.f, 0.f, 0.f, 0.f);
    #pragma unroll
    for (int k = 0; k < KNN_K; ++k) {
        acc.x += s[k] * vr[k].x; acc.y += s[k] * vr[k].y;
        acc.z += s[k] * vr[k].z; acc.w += s[k] * vr[k].w;
    }
    acc.x *= inv; acc.y *= inv; acc.z *= inv; acc.w *= inv;

    *reinterpret_cast<float4*>(out + (size_t)pt * HIDDEN_ + col) = acc;
}

extern "C" void kernel_launch(void* const* d_in, const int* in_sizes, int n_in,
                              void* d_out, int out_size, void* d_ws, size_t ws_size,
                              hipStream_t stream) {
    const float* keys    = (const float*)d_in[0];
    const float* queries = (const float*)d_in[1];
    const float* values  = (const float*)d_in[2];
    const int*   nbr     = (const int*)d_in[3];
    float*       out     = (float*)d_out;

    const int n_pts = in_sizes[3] / KNN_K;       // 50000
    const int waves_per_block = 4;               // 256 threads
    const int blocks = (n_pts + waves_per_block - 1) / waves_per_block;
    knn_attn_kernel<<<blocks, 256, 0, stream>>>(keys, queries, values, nbr, out, n_pts);
}